// Round 4
// 367.718 us; speedup vs baseline: 1.1014x; 1.1014x over previous
//
#include <hip/hip_runtime.h>
#include <hip/hip_bf16.h>

// Problem: B,T,D = 32,4096,128. Masked last/next-observation linear interp.
// v2 (resubmit x3; rounds 1-3 were broker GPUAcquisitionTimeouts, no data):
// LDS staging -> per-thread REGISTER staging (LDS was per-column-private;
// 52KB LDS capped occupancy at 3 blocks/CU). Boundary searches batched 8
// rows/round (was 1 row per serial latency hop). Staged value/time-delta in
// fp16 (exact for bf16 inputs; times themselves kept fp32 so denom==0
// semantics are unchanged). Output fp32, nontemporal (no reuse).
#define Bq 32
#define Tq 4096
#define Dq 128
#define Lseg 32
#define NSEG (Tq / Lseg)   // 128
#define SRCH 8             // rows probed per search latency-round

__device__ __forceinline__ float bfbits2f(unsigned short u) {
    return __uint_as_float(((unsigned int)u) << 16);
}
__device__ __forceinline__ unsigned short f2hbits(float x) {
    union { _Float16 h; unsigned short s; } cv;
    cv.h = (_Float16)x;
    return cv.s;
}
__device__ __forceinline__ float hbits2f(unsigned short u) {
    union { unsigned short s; _Float16 h; } cv;
    cv.s = u;
    return (float)cv.h;
}
__device__ __forceinline__ float ldval(const void* p, int idx, int f32) {
    if (f32) return ((const float*)p)[idx];
    return bfbits2f(((const unsigned short*)p)[idx]);
}
__device__ __forceinline__ bool ldmask(const void* p, int idx, int mode) {
    switch (mode) {
        case 1:  return ((const int*)p)[idx] != 0;            // int32 0/1
        case 2:  return ((const unsigned short*)p)[idx] != 0; // bf16 0/1.0
        case 3:  return ((const unsigned int*)p)[idx] != 0;   // fp32 0/1.0
        default: return ((const unsigned char*)p)[idx] != 0;  // bool8
    }
}

__global__ __launch_bounds__(128, 4) void interp_kernel(
    const void* __restrict__ values,
    const void* __restrict__ times,
    const void* __restrict__ mask,
    float* __restrict__ out)                 // fp32 output
{
    const int lane = threadIdx.x & 63;

    // ---- in-block dtype detection (wave-uniform, L2-hot) ----
    int mmode, f32;
    {
        const unsigned int* mu = (const unsigned int*)mask;
        int bad_f32 = 0, bad_b16 = 0, off_nz = 0;
        for (int j = lane; j < 1024; j += 64) {       // first 4096 bytes of mask
            unsigned int w = mu[j];
            if (w != 0u && w != 0x3F800000u) bad_f32 = 1;
            unsigned int h0 = w & 0xFFFFu, h1 = w >> 16;
            if ((h0 != 0u && h0 != 0x3F80u) || (h1 != 0u && h1 != 0x3F80u)) bad_b16 = 1;
            if (w & 0xFFFFFF00u) off_nz = 1;
        }
        if      (__ballot(bad_f32) == 0ull) mmode = 3;
        else if (__ballot(bad_b16) == 0ull) mmode = 2;
        else if (__ballot(off_nz)  == 0ull) mmode = 1;
        else                                mmode = 0;

        const unsigned short* tu = (const unsigned short*)times;
        int good = 0;
        for (int k = lane; k < 256; k += 64) {        // even u16s of first 256 elems
            int ex = (tu[2 * k] >> 7) & 0xFF;         // bf16 exponent field
            if (ex >= 118 && ex <= 142) good++;
        }
        for (int off = 32; off; off >>= 1) good += __shfl_xor(good, off, 64);
        f32 = (good < 128) ? 1 : 0;                   // bf16 passes ~100%, fp32 ~10%
    }

    const int b   = blockIdx.x >> 7;          // / NSEG
    const int s   = blockIdx.x & (NSEG - 1);
    const int d   = threadIdx.x;
    const int sLo = s * Lseg;
    const int sHi = sLo + Lseg;
    const int base = b * Tq * Dq + d;

    // ---- backward boundary: first observation at row >= sHi (batched) ----
    float bx = 0.f, bt;
    {
        int found = 0, nr = 0;
        for (int r = sHi; r < Tq; r += SRCH) {
            if (__ballot(!found) == 0ull) break;
            int hit[SRCH];
            #pragma unroll
            for (int j = 0; j < SRCH; ++j) {          // SRCH independent loads/round
                int rj = r + j;
                int rc = rj < Tq ? rj : Tq - 1;       // clamp: stay in-bounds
                hit[j] = (int)ldmask(mask, base + rc * Dq, mmode) & (int)(rj < Tq);
            }
            #pragma unroll
            for (int j = 0; j < SRCH; ++j)
                if (!found && hit[j]) { nr = r + j; found = 1; }
        }
        if (found) {
            bx = ldval(values, base + nr * Dq, f32);
            bt = ldval(times,  base + nr * Dq, f32);
        } else {
            bt = ldval(times, base + (Tq - 1) * Dq, f32);   // t_max (monotone)
        }
    }

    // ---- forward boundary: last observation at row < sLo (batched) ----
    float fx = 0.f, ft;
    {
        int found = 0, nr = 0;
        for (int r = sLo - 1; r >= 0; r -= SRCH) {
            if (__ballot(!found) == 0ull) break;
            int hit[SRCH];
            #pragma unroll
            for (int j = 0; j < SRCH; ++j) {
                int rj = r - j;
                int rc = rj > 0 ? rj : 0;
                hit[j] = (int)ldmask(mask, base + rc * Dq, mmode) & (int)(rj >= 0);
            }
            #pragma unroll
            for (int j = 0; j < SRCH; ++j)
                if (!found && hit[j]) { nr = r - j; found = 1; }
        }
        if (found) {
            fx = ldval(values, base + nr * Dq, f32);
            ft = ldval(times,  base + nr * Dq, f32);
        } else {
            ft = ldval(times, base, f32);             // times[b,0,d]
        }
    }

    // ---- backward sweep: per-row next-obs state into REGISTERS ----
    // tm fp32 (exact -> ft updates and denom==0 test unchanged vs v1);
    // nx / (t_next - tm) / v staged as fp16 pairs (fp16 holds any in-range
    // bf16 exactly; fp32-input path error <= 2^-11 rel, better than v1's bf16).
    float        tmA[Lseg];          // 32 VGPR
    unsigned int nxP[Lseg / 2];      // 16 VGPR: next value, fp16 x2
    unsigned int dtP[Lseg / 2];      // 16 VGPR: t_next - tm, fp16 x2
    unsigned int vvP[Lseg / 2];      // 16 VGPR: this value, fp16 x2
    unsigned int mbits = 0;

    #pragma unroll
    for (int rr = Lseg - 1; rr >= 0; --rr) {          // full unroll: static idx
        const int idx = base + (sLo + rr) * Dq;
        float v  = ldval(values, idx, f32);
        float tm = ldval(times,  idx, f32);
        bool  m  = ldmask(mask,  idx, mmode);
        if (m) { bx = v; bt = tm; mbits |= (1u << rr); }
        tmA[rr] = tm;
        unsigned int xb = f2hbits(bx);
        unsigned int db = f2hbits(bt - tm);
        unsigned int vb = f2hbits(v);
        if (rr & 1) {                                  // odd rr visited first
            nxP[rr >> 1] = xb << 16;
            dtP[rr >> 1] = db << 16;
            vvP[rr >> 1] = vb << 16;
        } else {
            nxP[rr >> 1] |= xb;
            dtP[rr >> 1] |= db;
            vvP[rr >> 1] |= vb;
        }
    }

    // ---- forward sweep: update last-obs state, emit fp32 ----
    // out = (fx*(nt-tm) + nx*(tm-ft)) / (nt-ft), with nt-tm = dtn staged,
    // tm-ft = a, denom = dtn + a.  Weights sum to 1 exactly regardless of
    // dtn rounding; denom==0 <=> dtn==0 && a==0 <=> reference's denom==0.
    #pragma unroll
    for (int rr = 0; rr < Lseg; ++rr) {
        const int sh = (rr & 1) << 4;
        float tm  = tmA[rr];
        float v   = hbits2f((unsigned short)(vvP[rr >> 1] >> sh));
        float dtn = hbits2f((unsigned short)(dtP[rr >> 1] >> sh));
        float nx  = hbits2f((unsigned short)(nxP[rr >> 1] >> sh));
        bool  m   = (mbits >> rr) & 1u;
        float ox;
        if (m) {
            fx = v; ft = tm;
            ox = v;
        } else {
            float a     = tm - ft;
            float denom = dtn + a;
            float num   = fx * dtn + nx * a;
            ox = (denom != 0.f) ? (num / denom) : 0.f;
        }
        __builtin_nontemporal_store(ox, &out[base + (sLo + rr) * Dq]);
    }
}

extern "C" void kernel_launch(void* const* d_in, const int* in_sizes, int n_in,
                              void* d_out, int out_size, void* d_ws, size_t ws_size,
                              hipStream_t stream) {
    const void* values = d_in[0];
    const void* times  = d_in[1];
    const void* mask   = d_in[2];
    float* out = (float*)d_out;               // reference output dtype = float32
    (void)d_ws; (void)ws_size;

    interp_kernel<<<Bq * NSEG, 128, 0, stream>>>(values, times, mask, out);
}

// Round 10
// 325.780 us; speedup vs baseline: 1.2432x; 1.1287x over previous
//
#include <hip/hip_runtime.h>
#include <hip/hip_bf16.h>

// Problem: B,T,D = 32,4096,128. Masked last/next-observation linear interp.
// v3 (resubmit x5; rounds 5-9 were broker GPUAcquisitionTimeouts, no data):
// v2's staging "arrays" were never promoted to registers (VGPR_Count=64,
// WRITE_SIZE 3x, FETCH +69MiB => allocas went to scratch; SROA runs before
// unroll so #pragma unroll didn't make indices static early enough — rule
// #20). Fix: NAMED scalar staging registers via macros, zero arrays in the
// kernel. Also: plain stores (v1 evidence: exactly 64MiB WRITE) and
// speculative value/time loads fused into the mask probes (saves the
// dependent found->fetch round in each boundary search).
#define Bq 32
#define Tq 4096
#define Dq 128
#define Lseg 32
#define NSEG (Tq / Lseg)   // 128
#define SRCH 8             // rows probed per search latency-round

__device__ __forceinline__ float bfbits2f(unsigned short u) {
    return __uint_as_float(((unsigned int)u) << 16);
}
__device__ __forceinline__ unsigned short f2hbits(float x) {
    union { _Float16 h; unsigned short s; } cv;
    cv.h = (_Float16)x;
    return cv.s;
}
__device__ __forceinline__ float hbits2f(unsigned short u) {
    union { unsigned short s; _Float16 h; } cv;
    cv.s = u;
    return (float)cv.h;
}
__device__ __forceinline__ float ldval(const void* p, int idx, int f32) {
    if (f32) return ((const float*)p)[idx];
    return bfbits2f(((const unsigned short*)p)[idx]);
}
__device__ __forceinline__ bool ldmask(const void* p, int idx, int mode) {
    switch (mode) {
        case 1:  return ((const int*)p)[idx] != 0;            // int32 0/1
        case 2:  return ((const unsigned short*)p)[idx] != 0; // bf16 0/1.0
        case 3:  return ((const unsigned int*)p)[idx] != 0;   // fp32 0/1.0
        default: return ((const unsigned char*)p)[idx] != 0;  // bool8
    }
}

// ---- named staging registers: pair q = rows 2q (lo16) and 2q+1 (hi16) ----
#define DECLQ(q) float tmL_##q, tmH_##q; unsigned int pnx_##q, pdt_##q, pvv_##q;

// backward sweep steps (visit hi row first, then lo row)
#define BHI(q) { \
    const int rr = 2*(q) + 1; \
    const int idx = base + (sLo + rr) * Dq; \
    float v  = ldval(values, idx, f32); \
    float tm = ldval(times,  idx, f32); \
    bool  m  = ldmask(mask,  idx, mmode); \
    if (m) { bx = v; bt = tm; mbits |= (1u << rr); } \
    tmH_##q = tm; \
    pnx_##q = ((unsigned int)f2hbits(bx)) << 16; \
    pdt_##q = ((unsigned int)f2hbits(bt - tm)) << 16; \
    pvv_##q = ((unsigned int)f2hbits(v)) << 16; }

#define BLO(q) { \
    const int rr = 2*(q); \
    const int idx = base + (sLo + rr) * Dq; \
    float v  = ldval(values, idx, f32); \
    float tm = ldval(times,  idx, f32); \
    bool  m  = ldmask(mask,  idx, mmode); \
    if (m) { bx = v; bt = tm; mbits |= (1u << rr); } \
    tmL_##q = tm; \
    pnx_##q |= (unsigned int)f2hbits(bx); \
    pdt_##q |= (unsigned int)f2hbits(bt - tm); \
    pvv_##q |= (unsigned int)f2hbits(v); }

// forward sweep steps. out = (fx*dtn + nx*a)/(dtn + a); weights sum to 1, so
// dtn fp16 rounding stays within tolerance and denom==0 <=> dtn==0 && a==0.
#define FEMIT(rr, tm, v, dtn, nx) { \
    bool m = (mbits >> (rr)) & 1u; \
    float ox; \
    if (m) { fx = (v); ft = (tm); ox = (v); } \
    else { \
        float a = (tm) - ft; \
        float denom = (dtn) + a; \
        float num = fx * (dtn) + (nx) * a; \
        ox = (denom != 0.f) ? (num / denom) : 0.f; \
    } \
    out[base + (sLo + (rr)) * Dq] = ox; }

#define FLO(q) { \
    float tm  = tmL_##q; \
    float v   = hbits2f((unsigned short)(pvv_##q & 0xFFFFu)); \
    float dtn = hbits2f((unsigned short)(pdt_##q & 0xFFFFu)); \
    float nx  = hbits2f((unsigned short)(pnx_##q & 0xFFFFu)); \
    FEMIT(2*(q), tm, v, dtn, nx) }

#define FHI(q) { \
    float tm  = tmH_##q; \
    float v   = hbits2f((unsigned short)(pvv_##q >> 16)); \
    float dtn = hbits2f((unsigned short)(pdt_##q >> 16)); \
    float nx  = hbits2f((unsigned short)(pnx_##q >> 16)); \
    FEMIT(2*(q)+1, tm, v, dtn, nx) }

// boundary-search probes: mask + SPECULATIVE value/time in one round
#define BPROBE(j) \
    int bm##j; float bv##j, btm##j; { \
        int rj = r + (j); int rc = rj < Tq ? rj : Tq - 1; \
        int idx = base + rc * Dq; \
        bm##j  = (int)ldmask(mask, idx, mmode) & (int)(rj < Tq); \
        bv##j  = ldval(values, idx, f32); \
        btm##j = ldval(times,  idx, f32); }
#define BSEL(j) if (!found && bm##j) { bx = bv##j; bt = btm##j; found = 1; }

#define FPROBE(j) \
    int fm##j; float fv##j, ftm##j; { \
        int rj = r - (j); int rc = rj > 0 ? rj : 0; \
        int idx = base + rc * Dq; \
        fm##j  = (int)ldmask(mask, idx, mmode) & (int)(rj >= 0); \
        fv##j  = ldval(values, idx, f32); \
        ftm##j = ldval(times,  idx, f32); }
#define FSEL(j) if (!found && fm##j) { fx = fv##j; ft = ftm##j; found = 1; }

__global__ __launch_bounds__(128, 3) void interp_kernel(
    const void* __restrict__ values,
    const void* __restrict__ times,
    const void* __restrict__ mask,
    float* __restrict__ out)                 // fp32 output
{
    const int lane = threadIdx.x & 63;

    // ---- in-block dtype detection (wave-uniform, L2-hot) ----
    int mmode, f32;
    {
        const unsigned int* mu = (const unsigned int*)mask;
        int bad_f32 = 0, bad_b16 = 0, off_nz = 0;
        for (int j = lane; j < 1024; j += 64) {       // first 4096 bytes of mask
            unsigned int w = mu[j];
            if (w != 0u && w != 0x3F800000u) bad_f32 = 1;
            unsigned int h0 = w & 0xFFFFu, h1 = w >> 16;
            if ((h0 != 0u && h0 != 0x3F80u) || (h1 != 0u && h1 != 0x3F80u)) bad_b16 = 1;
            if (w & 0xFFFFFF00u) off_nz = 1;
        }
        if      (__ballot(bad_f32) == 0ull) mmode = 3;
        else if (__ballot(bad_b16) == 0ull) mmode = 2;
        else if (__ballot(off_nz)  == 0ull) mmode = 1;
        else                                mmode = 0;

        const unsigned short* tu = (const unsigned short*)times;
        int good = 0;
        for (int k = lane; k < 256; k += 64) {        // even u16s of first 256 elems
            int ex = (tu[2 * k] >> 7) & 0xFF;         // bf16 exponent field
            if (ex >= 118 && ex <= 142) good++;
        }
        for (int off = 32; off; off >>= 1) good += __shfl_xor(good, off, 64);
        f32 = (good < 128) ? 1 : 0;                   // bf16 passes ~100%, fp32 ~10%
    }

    const int b   = blockIdx.x >> 7;          // / NSEG
    const int s   = blockIdx.x & (NSEG - 1);
    const int d   = threadIdx.x;
    const int sLo = s * Lseg;
    const int sHi = sLo + Lseg;
    const int base = b * Tq * Dq + d;

    // ---- backward boundary: first observation at row >= sHi ----
    float bx = 0.f, bt = 0.f;
    {
        int found = 0;
        for (int r = sHi; r < Tq; r += SRCH) {
            if (__ballot(!found) == 0ull) break;
            BPROBE(0) BPROBE(1) BPROBE(2) BPROBE(3)
            BPROBE(4) BPROBE(5) BPROBE(6) BPROBE(7)
            BSEL(0) BSEL(1) BSEL(2) BSEL(3)
            BSEL(4) BSEL(5) BSEL(6) BSEL(7)
        }
        if (!found) bt = ldval(times, base + (Tq - 1) * Dq, f32); // t_max
    }

    // ---- forward boundary: last observation at row < sLo ----
    float fx = 0.f, ft = 0.f;
    {
        int found = 0;
        for (int r = sLo - 1; r >= 0; r -= SRCH) {
            if (__ballot(!found) == 0ull) break;
            FPROBE(0) FPROBE(1) FPROBE(2) FPROBE(3)
            FPROBE(4) FPROBE(5) FPROBE(6) FPROBE(7)
            FSEL(0) FSEL(1) FSEL(2) FSEL(3)
            FSEL(4) FSEL(5) FSEL(6) FSEL(7)
        }
        if (!found) ft = ldval(times, base, f32);     // times[b,0,d]
    }

    // ---- backward sweep into NAMED registers (no arrays -> no scratch) ----
    DECLQ(0)  DECLQ(1)  DECLQ(2)  DECLQ(3)
    DECLQ(4)  DECLQ(5)  DECLQ(6)  DECLQ(7)
    DECLQ(8)  DECLQ(9)  DECLQ(10) DECLQ(11)
    DECLQ(12) DECLQ(13) DECLQ(14) DECLQ(15)
    unsigned int mbits = 0;

    BHI(15) BLO(15) BHI(14) BLO(14) BHI(13) BLO(13) BHI(12) BLO(12)
    BHI(11) BLO(11) BHI(10) BLO(10) BHI(9)  BLO(9)  BHI(8)  BLO(8)
    BHI(7)  BLO(7)  BHI(6)  BLO(6)  BHI(5)  BLO(5)  BHI(4)  BLO(4)
    BHI(3)  BLO(3)  BHI(2)  BLO(2)  BHI(1)  BLO(1)  BHI(0)  BLO(0)

    // ---- forward sweep: update last-obs state, emit fp32 ----
    FLO(0)  FHI(0)  FLO(1)  FHI(1)  FLO(2)  FHI(2)  FLO(3)  FHI(3)
    FLO(4)  FHI(4)  FLO(5)  FHI(5)  FLO(6)  FHI(6)  FLO(7)  FHI(7)
    FLO(8)  FHI(8)  FLO(9)  FHI(9)  FLO(10) FHI(10) FLO(11) FHI(11)
    FLO(12) FHI(12) FLO(13) FHI(13) FLO(14) FHI(14) FLO(15) FHI(15)
}

extern "C" void kernel_launch(void* const* d_in, const int* in_sizes, int n_in,
                              void* d_out, int out_size, void* d_ws, size_t ws_size,
                              hipStream_t stream) {
    const void* values = d_in[0];
    const void* times  = d_in[1];
    const void* mask   = d_in[2];
    float* out = (float*)d_out;               // reference output dtype = float32
    (void)d_ws; (void)ws_size;

    interp_kernel<<<Bq * NSEG, 128, 0, stream>>>(values, times, mask, out);
}

// Round 13
// 314.345 us; speedup vs baseline: 1.2884x; 1.0364x over previous
//
#include <hip/hip_runtime.h>
#include <hip/hip_bf16.h>

// Problem: B,T,D = 32,4096,128. Masked last/next-observation linear interp.
// v4 (resubmit x2; rounds 11-12 were broker GPUAcquisitionTimeouts, no data):
// v3 still spilled ~16 dwords/thread (VGPR=84=floor(512/6): compiler
// targeted 6 waves/SIMD and spilled the overflow; WRITE 96MiB = 64 output
// + 32 scratch). Fix: drop the pvv staging entirely — at masked rows the
// backward sweep sets bx=v BEFORE writing pnx, so pnx[rr]==f2hbits(v) and
// v is only consumed on the masked path; read v from pnx (bit-identical).
// State: 64 staged regs (tm fp32 x32, pnx x16, pdt x16) + ~20 working ->
// fits the 84-reg/6-wave target with zero spill.
#define Bq 32
#define Tq 4096
#define Dq 128
#define Lseg 32
#define NSEG (Tq / Lseg)   // 128
#define SRCH 8             // rows probed per search latency-round

__device__ __forceinline__ float bfbits2f(unsigned short u) {
    return __uint_as_float(((unsigned int)u) << 16);
}
__device__ __forceinline__ unsigned short f2hbits(float x) {
    union { _Float16 h; unsigned short s; } cv;
    cv.h = (_Float16)x;
    return cv.s;
}
__device__ __forceinline__ float hbits2f(unsigned short u) {
    union { unsigned short s; _Float16 h; } cv;
    cv.s = u;
    return (float)cv.h;
}
__device__ __forceinline__ float ldval(const void* p, int idx, int f32) {
    if (f32) return ((const float*)p)[idx];
    return bfbits2f(((const unsigned short*)p)[idx]);
}
__device__ __forceinline__ bool ldmask(const void* p, int idx, int mode) {
    switch (mode) {
        case 1:  return ((const int*)p)[idx] != 0;            // int32 0/1
        case 2:  return ((const unsigned short*)p)[idx] != 0; // bf16 0/1.0
        case 3:  return ((const unsigned int*)p)[idx] != 0;   // fp32 0/1.0
        default: return ((const unsigned char*)p)[idx] != 0;  // bool8
    }
}

// ---- named staging registers: pair q = rows 2q (lo16) and 2q+1 (hi16) ----
// pnx: next-observed value (fp16 bits). At masked rows this IS the row's own
// value (bx=v was set before the write), so no separate pvv staging needed.
#define DECLQ(q) float tmL_##q, tmH_##q; unsigned int pnx_##q, pdt_##q;

// backward sweep steps (visit hi row first, then lo row)
#define BHI(q) { \
    const int rr = 2*(q) + 1; \
    const int idx = base + (sLo + rr) * Dq; \
    float v  = ldval(values, idx, f32); \
    float tm = ldval(times,  idx, f32); \
    bool  m  = ldmask(mask,  idx, mmode); \
    if (m) { bx = v; bt = tm; mbits |= (1u << rr); } \
    tmH_##q = tm; \
    pnx_##q = ((unsigned int)f2hbits(bx)) << 16; \
    pdt_##q = ((unsigned int)f2hbits(bt - tm)) << 16; }

#define BLO(q) { \
    const int rr = 2*(q); \
    const int idx = base + (sLo + rr) * Dq; \
    float v  = ldval(values, idx, f32); \
    float tm = ldval(times,  idx, f32); \
    bool  m  = ldmask(mask,  idx, mmode); \
    if (m) { bx = v; bt = tm; mbits |= (1u << rr); } \
    tmL_##q = tm; \
    pnx_##q |= (unsigned int)f2hbits(bx); \
    pdt_##q |= (unsigned int)f2hbits(bt - tm); }

// forward sweep. Masked row: v == nx (see pnx invariant) -> out=nx, fx=nx,
// ft=tm. Unmasked: out = (fx*dtn + nx*a)/(dtn + a); weights sum to 1, so
// dtn fp16 rounding stays within tolerance and denom==0 <=> dtn==0 && a==0.
#define FEMIT(rr, tm, dtn, nx) { \
    bool m = (mbits >> (rr)) & 1u; \
    float ox; \
    if (m) { fx = (nx); ft = (tm); ox = (nx); } \
    else { \
        float a = (tm) - ft; \
        float denom = (dtn) + a; \
        float num = fx * (dtn) + (nx) * a; \
        ox = (denom != 0.f) ? (num / denom) : 0.f; \
    } \
    out[base + (sLo + (rr)) * Dq] = ox; }

#define FLO(q) { \
    float tm  = tmL_##q; \
    float dtn = hbits2f((unsigned short)(pdt_##q & 0xFFFFu)); \
    float nx  = hbits2f((unsigned short)(pnx_##q & 0xFFFFu)); \
    FEMIT(2*(q), tm, dtn, nx) }

#define FHI(q) { \
    float tm  = tmH_##q; \
    float dtn = hbits2f((unsigned short)(pdt_##q >> 16)); \
    float nx  = hbits2f((unsigned short)(pnx_##q >> 16)); \
    FEMIT(2*(q)+1, tm, dtn, nx) }

// boundary-search probes: mask + SPECULATIVE value/time in one round
#define BPROBE(j) \
    int bm##j; float bv##j, btm##j; { \
        int rj = r + (j); int rc = rj < Tq ? rj : Tq - 1; \
        int idx = base + rc * Dq; \
        bm##j  = (int)ldmask(mask, idx, mmode) & (int)(rj < Tq); \
        bv##j  = ldval(values, idx, f32); \
        btm##j = ldval(times,  idx, f32); }
#define BSEL(j) if (!found && bm##j) { bx = bv##j; bt = btm##j; found = 1; }

#define FPROBE(j) \
    int fm##j; float fv##j, ftm##j; { \
        int rj = r - (j); int rc = rj > 0 ? rj : 0; \
        int idx = base + rc * Dq; \
        fm##j  = (int)ldmask(mask, idx, mmode) & (int)(rj >= 0); \
        fv##j  = ldval(values, idx, f32); \
        ftm##j = ldval(times,  idx, f32); }
#define FSEL(j) if (!found && fm##j) { fx = fv##j; ft = ftm##j; found = 1; }

__global__ __launch_bounds__(128, 3) void interp_kernel(
    const void* __restrict__ values,
    const void* __restrict__ times,
    const void* __restrict__ mask,
    float* __restrict__ out)                 // fp32 output
{
    const int lane = threadIdx.x & 63;

    // ---- in-block dtype detection (wave-uniform, L2-hot) ----
    int mmode, f32;
    {
        const unsigned int* mu = (const unsigned int*)mask;
        int bad_f32 = 0, bad_b16 = 0, off_nz = 0;
        for (int j = lane; j < 1024; j += 64) {       // first 4096 bytes of mask
            unsigned int w = mu[j];
            if (w != 0u && w != 0x3F800000u) bad_f32 = 1;
            unsigned int h0 = w & 0xFFFFu, h1 = w >> 16;
            if ((h0 != 0u && h0 != 0x3F80u) || (h1 != 0u && h1 != 0x3F80u)) bad_b16 = 1;
            if (w & 0xFFFFFF00u) off_nz = 1;
        }
        if      (__ballot(bad_f32) == 0ull) mmode = 3;
        else if (__ballot(bad_b16) == 0ull) mmode = 2;
        else if (__ballot(off_nz)  == 0ull) mmode = 1;
        else                                mmode = 0;

        const unsigned short* tu = (const unsigned short*)times;
        int good = 0;
        for (int k = lane; k < 256; k += 64) {        // even u16s of first 256 elems
            int ex = (tu[2 * k] >> 7) & 0xFF;         // bf16 exponent field
            if (ex >= 118 && ex <= 142) good++;
        }
        for (int off = 32; off; off >>= 1) good += __shfl_xor(good, off, 64);
        f32 = (good < 128) ? 1 : 0;                   // bf16 passes ~100%, fp32 ~10%
    }

    const int b   = blockIdx.x >> 7;          // / NSEG
    const int s   = blockIdx.x & (NSEG - 1);
    const int d   = threadIdx.x;
    const int sLo = s * Lseg;
    const int sHi = sLo + Lseg;
    const int base = b * Tq * Dq + d;

    // ---- backward boundary: first observation at row >= sHi ----
    float bx = 0.f, bt = 0.f;
    {
        int found = 0;
        for (int r = sHi; r < Tq; r += SRCH) {
            if (__ballot(!found) == 0ull) break;
            BPROBE(0) BPROBE(1) BPROBE(2) BPROBE(3)
            BPROBE(4) BPROBE(5) BPROBE(6) BPROBE(7)
            BSEL(0) BSEL(1) BSEL(2) BSEL(3)
            BSEL(4) BSEL(5) BSEL(6) BSEL(7)
        }
        if (!found) bt = ldval(times, base + (Tq - 1) * Dq, f32); // t_max
    }

    // ---- forward boundary: last observation at row < sLo ----
    float fx = 0.f, ft = 0.f;
    {
        int found = 0;
        for (int r = sLo - 1; r >= 0; r -= SRCH) {
            if (__ballot(!found) == 0ull) break;
            FPROBE(0) FPROBE(1) FPROBE(2) FPROBE(3)
            FPROBE(4) FPROBE(5) FPROBE(6) FPROBE(7)
            FSEL(0) FSEL(1) FSEL(2) FSEL(3)
            FSEL(4) FSEL(5) FSEL(6) FSEL(7)
        }
        if (!found) ft = ldval(times, base, f32);     // times[b,0,d]
    }

    // ---- backward sweep into NAMED registers (no arrays -> no scratch) ----
    DECLQ(0)  DECLQ(1)  DECLQ(2)  DECLQ(3)
    DECLQ(4)  DECLQ(5)  DECLQ(6)  DECLQ(7)
    DECLQ(8)  DECLQ(9)  DECLQ(10) DECLQ(11)
    DECLQ(12) DECLQ(13) DECLQ(14) DECLQ(15)
    unsigned int mbits = 0;

    BHI(15) BLO(15) BHI(14) BLO(14) BHI(13) BLO(13) BHI(12) BLO(12)
    BHI(11) BLO(11) BHI(10) BLO(10) BHI(9)  BLO(9)  BHI(8)  BLO(8)
    BHI(7)  BLO(7)  BHI(6)  BLO(6)  BHI(5)  BLO(5)  BHI(4)  BLO(4)
    BHI(3)  BLO(3)  BHI(2)  BLO(2)  BHI(1)  BLO(1)  BHI(0)  BLO(0)

    // ---- forward sweep: update last-obs state, emit fp32 ----
    FLO(0)  FHI(0)  FLO(1)  FHI(1)  FLO(2)  FHI(2)  FLO(3)  FHI(3)
    FLO(4)  FHI(4)  FLO(5)  FHI(5)  FLO(6)  FHI(6)  FLO(7)  FHI(7)
    FLO(8)  FHI(8)  FLO(9)  FHI(9)  FLO(10) FHI(10) FLO(11) FHI(11)
    FLO(12) FHI(12) FLO(13) FHI(13) FLO(14) FHI(14) FLO(15) FHI(15)
}

extern "C" void kernel_launch(void* const* d_in, const int* in_sizes, int n_in,
                              void* d_out, int out_size, void* d_ws, size_t ws_size,
                              hipStream_t stream) {
    const void* values = d_in[0];
    const void* times  = d_in[1];
    const void* mask   = d_in[2];
    float* out = (float*)d_out;               // reference output dtype = float32
    (void)d_ws; (void)ws_size;

    interp_kernel<<<Bq * NSEG, 128, 0, stream>>>(values, times, mask, out);
}